// Round 11
// baseline (384.379 us; speedup 1.0000x reference)
//
#include <hip/hip_runtime.h>
#include <cstdint>
#include <cstddef>
#include <math.h>

#define NN 100000
#define NE 1600000
#define DCAP 64                 // padded per-node capacity (max deg ~45 for Poisson(16))

#define MS 40                   // MFMA LDS row stride in u16 (80 B: 16-B aligned frags, 2-way banks)

typedef unsigned short u16;
typedef __attribute__((ext_vector_type(8))) short bf16x8;
typedef __attribute__((ext_vector_type(4))) float f32x4;

__device__ __forceinline__ float bf2f(u16 u) {
    union { unsigned i; float f; } c; c.i = ((unsigned)u) << 16; return c.f;
}
__device__ __forceinline__ u16 f2bf(float f) {  // round-to-nearest-even
    union { float f; unsigned int i; } c; c.f = f;
    unsigned int lsb = (c.i >> 16) & 1u;
    return (u16)((c.i + 0x7fffu + lsb) >> 16);
}

__device__ __forceinline__ int load_idx(const void* ei, int isI64, int pos) {
    if (isI64) return (int)((const long long*)ei)[pos];
    return ((const int*)ei)[pos];
}

// ---------- R21: direct CSR build (replaces k_build + k_sort) ----------
// One pass over edges: slot = atomicAdd(&cnt[dst]) -> csr_pad[dst*64+slot]=src.
// 1.6M atomics over 100K counters (16/ctr, low contention), full TLP
// (409K threads vs old 400-block grid-starved build). No 6.4 MB
// intermediate, no counting sort. Slot clamped at DCAP (P(deg>64)~1e-20).
#define DB 1600                 // blocks
#define DT (DB * 256)           // total threads
__global__ __launch_bounds__(256) void k_direct(const void* __restrict__ ei,
                                                int* __restrict__ cnt,
                                                int* __restrict__ csr_pad) {
    __shared__ int anynz;
    const int* p = (const int*)ei;
    if (threadIdx.x == 0) anynz = 0;
    __syncthreads();
    int nz = 0;
    for (int i = threadIdx.x; i < 1024; i += 256) nz |= (p[2 * i + 1] != 0);
    if (nz) anynz = 1;   // benign race
    __syncthreads();
    int isI64 = (anynz == 0);

    int tg = blockIdx.x * 256 + threadIdx.x;
    for (int e = tg; e < NE; e += DT) {
        int s = load_idx(ei, isI64, e);
        int d = load_idx(ei, isI64, NE + e);
        int slot = atomicAdd(&cnt[d], 1);
        if (slot < DCAP) csr_pad[(size_t)d * DCAP + slot] = s;
    }
}

// ---------- finalize: dis[n] = rsqrt(deg+1) ----------
__global__ __launch_bounds__(256) void k_fin(const int* __restrict__ cnt,
                                             float* __restrict__ dis) {
    int n = blockIdx.x * 256 + threadIdx.x;
    if (n < NN) dis[n] = rsqrtf((float)(cnt[n] + 1));
}

// ---------- R19: MFMA GEMM (512 thr = 8 waves, 128 nodes/block) ----------
// g[n][j] = bf16( dis[n] * (act(x)[n][:] @ W[:][j]) ), via
// mfma_f32_16x16x32_bf16. x split hi+lo bf16 (2 MFMAs) -> only W's 2^-9
// rounding adds error. Verified R9: absmax unchanged, WIN -41 us.
template <int K, int FR, bool RELU>
__global__ __launch_bounds__(512) void k_gemm_m(const float* __restrict__ x,
                                                const float* __restrict__ W,
                                                const float* __restrict__ dis,
                                                u16* __restrict__ out) {
    __shared__ u16 Ah[128 * MS];   // 10,240 B  x-hi bf16
    __shared__ u16 Al[128 * MS];   // 10,240 B  x-lo bf16
    __shared__ u16 Bw[64 * MS];    //  5,120 B  W^T bf16 [col][k]
    const int tid = threadIdx.x;
    const int w = tid >> 6;        // wave 0..7 -> M-strip rows w*16..+16
    const int l = tid & 63;
    const int row16 = l & 15;
    const int kg = l >> 4;
    const int nbase = blockIdx.x * 128;

    f32x4 acc[4];
#pragma unroll
    for (int t = 0; t < 4; ++t) acc[t] = (f32x4){0.f, 0.f, 0.f, 0.f};

    for (int kc = 0; kc < K; kc += 32) {
        // ---- stage x (fp32 -> hi/lo bf16), 8 floats/thread ----
        {
            int r = tid >> 2;          // 0..127
            int cg = tid & 3;          // 8-float group
            int n = nbase + r;
            float vs[8];
#pragma unroll
            for (int j = 0; j < 8; ++j) vs[j] = 0.f;
            if (n < NN) {
                const float* xp = x + (size_t)n * K + kc + cg * 8;
                float4 v0 = *(const float4*)xp;
                float4 v1 = *(const float4*)(xp + 4);
                vs[0] = v0.x; vs[1] = v0.y; vs[2] = v0.z; vs[3] = v0.w;
                vs[4] = v1.x; vs[5] = v1.y; vs[6] = v1.z; vs[7] = v1.w;
            }
            if (RELU) {
#pragma unroll
                for (int j = 0; j < 8; ++j) vs[j] = fmaxf(vs[j], 0.f);
            }
            u16* ah = &Ah[r * MS + cg * 8];
            u16* al = &Al[r * MS + cg * 8];
#pragma unroll
            for (int j = 0; j < 8; j += 2) {
                u16 h0 = f2bf(vs[j]);
                u16 h1 = f2bf(vs[j + 1]);
                float r0 = vs[j] - bf2f(h0);
                float r1 = vs[j + 1] - bf2f(h1);
                *(unsigned*)&ah[j] = (unsigned)h0 | ((unsigned)h1 << 16);
                *(unsigned*)&al[j] = (unsigned)f2bf(r0) | ((unsigned)f2bf(r1) << 16);
            }
        }
        // ---- stage W transposed: Bw[col][k], zero-pad cols >= FR ----
        {
            int k = tid >> 4;          // 0..31
            int c0 = (tid & 15) * 4;   // 0..60
#pragma unroll
            for (int j = 0; j < 4; ++j) {
                int c = c0 + j;
                float wv = (c < FR) ? W[(size_t)(kc + k) * FR + c] : 0.f;
                Bw[c * MS + k] = f2bf(wv);
            }
        }
        __syncthreads();
        // ---- fragments + MFMA ----
        bf16x8 ah = *(const bf16x8*)&Ah[(w * 16 + row16) * MS + kg * 8];
        bf16x8 al = *(const bf16x8*)&Al[(w * 16 + row16) * MS + kg * 8];
#pragma unroll
        for (int t = 0; t < 4; ++t) {
            bf16x8 b = *(const bf16x8*)&Bw[(t * 16 + row16) * MS + kg * 8];
            acc[t] = __builtin_amdgcn_mfma_f32_16x16x32_bf16(ah, b, acc[t], 0, 0, 0);
            acc[t] = __builtin_amdgcn_mfma_f32_16x16x32_bf16(al, b, acc[t], 0, 0, 0);
        }
        __syncthreads();
    }
    // ---- epilogue: D[row=(kg*4+r)][col=row16] -> out[n][feat] ----
#pragma unroll
    for (int r = 0; r < 4; ++r) {
        int n = nbase + w * 16 + kg * 4 + r;
        if (n < NN) {
            float dv = dis[n];
#pragma unroll
            for (int t = 0; t < 4; ++t) {
                int feat = t * 16 + row16;
                if (feat < FR)
                    out[(size_t)n * FR + feat] = f2bf(dv * acc[t][r]);
            }
        }
    }
}

// ---------- R18 gather batch: B edges, dword (feat-pair) loads ----------
// MEASURED-OPTIMAL access shape (R18/R20 A/B): quarter-wave (16 lanes x
// 4 B) = exactly one 64-B line -> 2 line-requests/row, the minimum for a
// 128-B row. u16 form (4 req) = 48 us; dword = 43.3; u64 (2 lines per
// quarter-wave again) = 45.3. DO NOT change the load width.
template <int F, int B, bool MASK>
__device__ __forceinline__ float2 gb2(int myidx, int i, int lim, int eh,
                                      const u16* __restrict__ g, unsigned fp) {
    unsigned off[B / 2];
#pragma unroll
    for (int k = 0; k < B / 2; ++k) {
        int s = __shfl(myidx, i + 2 * k + eh);
        off[k] = (unsigned)s * (unsigned)(F * 2) + fp * 4u;
    }
    unsigned hv[B / 2];
#pragma unroll
    for (int k = 0; k < B / 2; ++k)
        hv[k] = *(const unsigned*)((const char*)g + off[k]);
    float x0 = 0.f, x1 = 0.f, y0 = 0.f, y1 = 0.f;
#pragma unroll
    for (int k = 0; k < B / 2; ++k) {
        float vx = bf2f((u16)(hv[k] & 0xffffu));
        float vy = bf2f((u16)(hv[k] >> 16));
        if (MASK) {
            bool ok = (i + 2 * k + eh) < lim;
            vx = ok ? vx : 0.f;
            vy = ok ? vy : 0.f;
        }
        if (k & 1) { x1 += vx; y1 += vy; }
        else       { x0 += vx; y0 += vy; }
    }
    float2 r; r.x = x0 + x1; r.y = y0 + y1; return r;
}

// ---------- R18 gather vs padded CSR: start = n*DCAP, len = min(cnt,64) ----
template <int F, bool SOFTMAX>
__global__ __launch_bounds__(256) void k_gather2(const int* __restrict__ cnt,
                                                 const int* __restrict__ csr_pad,
                                                 const float* __restrict__ dis,
                                                 const u16* __restrict__ g,
                                                 const float* __restrict__ b,
                                                 float* __restrict__ out) {
    int n = blockIdx.x * 4 + (threadIdx.x >> 6);   // grid exact: n < NN
    unsigned lane = threadIdx.x & 63;
    unsigned fc2 = lane & 31;                      // feature-pair id
    int eh = (int)(lane >> 5);                     // edge-half 0/1
    bool valid = (2u * fc2 < (unsigned)F);
    unsigned fp = valid ? fc2 : (unsigned)(F / 2 - 1);

    int start = n * DCAP;                          // SALU, no load
    int len   = __builtin_amdgcn_readfirstlane(cnt[n]);
    len = (len < DCAP) ? len : DCAP;
    float dvn = dis[n];

    unsigned sv = *(const unsigned*)((const char*)g
                      + (size_t)(unsigned)n * (unsigned)(F * 2) + fp * 4u);
    float2 acc;
    acc.x = eh ? 0.f : bf2f((u16)(sv & 0xffffu));
    acc.y = eh ? 0.f : bf2f((u16)(sv >> 16));

    int myidx = 0;
    if ((int)lane < len) myidx = csr_pad[start + (int)lane];
    int lim = len;

    if (lim > 0) {
        float2 t;
        if (lim >= 33) {
            int i = 0;
            for (; i + 16 <= lim; i += 16) {
                t = gb2<F, 16, false>(myidx, i, lim, eh, g, fp);
                acc.x += t.x; acc.y += t.y;
            }
            if (i < lim) {
                t = gb2<F, 16, true>(myidx, i, lim, eh, g, fp);
                acc.x += t.x; acc.y += t.y;
            }
        } else if (lim >= 17) {
            t = gb2<F, 32, true>(myidx, 0, lim, eh, g, fp);
            acc.x += t.x; acc.y += t.y;
        } else if (lim == 16) {
            t = gb2<F, 16, false>(myidx, 0, lim, eh, g, fp);
            acc.x += t.x; acc.y += t.y;
        } else {
            t = gb2<F, 16, true>(myidx, 0, lim, eh, g, fp);
            acc.x += t.x; acc.y += t.y;
        }
    }
    acc.x += __shfl_xor(acc.x, 32);
    acc.y += __shfl_xor(acc.y, 32);

    float vx = dvn * acc.x + b[2 * fp + 0];
    float vy = dvn * acc.y + b[2 * fp + 1];

    if (!SOFTMAX) {
        if (eh == 0 && valid) {
            float2 o; o.x = vx; o.y = vy;
            *(float2*)(out + (size_t)n * F + 2 * fp) = o;
        }
    } else {
        float m = valid ? fmaxf(vx, vy) : -INFINITY;
#pragma unroll
        for (int off = 16; off; off >>= 1) m = fmaxf(m, __shfl_xor(m, off));
        float ex = valid ? (__expf(vx - m) + __expf(vy - m)) : 0.f;
        float sum = ex;
#pragma unroll
        for (int off = 16; off; off >>= 1) sum += __shfl_xor(sum, off);
        if (eh == 0 && valid) {
            float ls = logf(sum);
            float2 o; o.x = vx - m - ls; o.y = vy - m - ls;
            *(float2*)(out + (size_t)n * F + 2 * fp) = o;
        }
    }
}

extern "C" void kernel_launch(void* const* d_in, const int* in_sizes, int n_in,
                              void* d_out, int out_size, void* d_ws, size_t ws_size,
                              hipStream_t stream) {
    const float* x  = (const float*)d_in[0];
    const void*  ei = d_in[1];
    const float* W1 = (const float*)d_in[2];
    const float* b1 = (const float*)d_in[3];
    const float* W2 = (const float*)d_in[4];
    const float* b2 = (const float*)d_in[5];
    const float* W3 = (const float*)d_in[6];
    const float* b3 = (const float*)d_in[7];
    float* out = (float*)d_out;

    char* ws = (char*)d_ws;
    size_t off = 0;
    auto alloc = [&](size_t bytes) { void* p = ws + off; off += (bytes + 255) & ~255ULL; return p; };
    int*   cnt     = (int*)alloc(NN * 4);                    // 0.4 MB
    float* dis     = (float*)alloc(NN * 4);                  // 0.4 MB
    int*   csr_pad = (int*)alloc((size_t)NN * DCAP * 4);     // 25.6 MB
    u16*   gbuf    = (u16*)alloc((size_t)NN * 64 * 2);       // 12.8 MB bf16 staging
    float* act     = (float*)alloc((size_t)NN * 64 * 4);     // 25.6 MB fp32 activations

    // CSR: direct padded scatter (1 pass) + finalize
    hipMemsetAsync(cnt, 0, NN * 4, stream);
    k_direct<<<DB, 256, 0, stream>>>(ei, cnt, csr_pad);
    k_fin<<<(NN + 255) / 256, 256, 0, stream>>>(cnt, dis);

    const int gemm_grid = (NN + 127) / 128;   // 782
    const int gather_grid = NN / 4;           // 25000 (exact)

    // layer 1: g1 = bf16(dis*(x@W1)); act = dis*(sum g1) + b1 (ReLU in next gemm)
    k_gemm_m<128, 64, false><<<gemm_grid, 512, 0, stream>>>(x, W1, dis, gbuf);
    k_gather2<64, false><<<gather_grid, 256, 0, stream>>>(cnt, csr_pad, dis, gbuf, b1, act);

    // layer 2
    k_gemm_m<64, 64, true><<<gemm_grid, 512, 0, stream>>>(act, W2, dis, gbuf);
    k_gather2<64, false><<<gather_grid, 256, 0, stream>>>(cnt, csr_pad, dis, gbuf, b2, act);

    // layer 3 + fused log_softmax (tight 40-wide staging rows)
    k_gemm_m<64, 40, true><<<gemm_grid, 512, 0, stream>>>(act, W3, dis, gbuf);
    k_gather2<40, true><<<gather_grid, 256, 0, stream>>>(cnt, csr_pad, dis, gbuf, b3, out);
}

// Round 12
// 292.178 us; speedup vs baseline: 1.3156x; 1.3156x over previous
//
#include <hip/hip_runtime.h>
#include <cstdint>
#include <cstddef>
#include <math.h>

#define NN 100000
#define NE 1600000
#define NB ((NN + 255) / 256)   // 391 node buckets (256 nodes each)
#define EB 800                  // build blocks (R22: 400->800, halves latency chain)
#define EPB (NE / EB)           // 2000 edges per block
#define CAP 5120                // padded bucket capacity (mean 4092, sigma~64)

#define MS 40                   // MFMA LDS row stride in u16 (80 B: 16-B aligned frags, 2-way banks)

typedef unsigned short u16;
typedef __attribute__((ext_vector_type(8))) short bf16x8;
typedef __attribute__((ext_vector_type(4))) float f32x4;

__device__ __forceinline__ float bf2f(u16 u) {
    union { unsigned i; float f; } c; c.i = ((unsigned)u) << 16; return c.f;
}
__device__ __forceinline__ u16 f2bf(float f) {  // round-to-nearest-even
    union { float f; unsigned int i; } c; c.f = f;
    unsigned int lsb = (c.i >> 16) & 1u;
    return (u16)((c.i + 0x7fffu + lsb) >> 16);
}

__device__ __forceinline__ int load_idx(const void* ei, int isI64, int pos) {
    if (isI64) return (int)((const long long*)ei)[pos];
    return ((const int*)ei)[pos];
}

// ---------- CSR phase A: detect + hist + scatter into padded buckets ----------
// LDS-staged, bucket-coalesced writes. DO NOT replace with direct scatter:
// R21 measured 150 us (4-B random stores -> 64-B write-allocate, 96 MB HBM).
__global__ __launch_bounds__(256) void k_build(const void* __restrict__ ei,
                                               int* __restrict__ cursor,
                                               int* __restrict__ csr_tmp) {
    __shared__ int sbuf[EPB];      // 8,000 B
    __shared__ int dbuf[EPB];      // 8,000 B
    __shared__ int cnt[NB];
    __shared__ int basel[NB];
    __shared__ int anynz;

    const int* p = (const int*)ei;
    if (threadIdx.x == 0) anynz = 0;
    for (int i = threadIdx.x; i < NB; i += 256) cnt[i] = 0;
    __syncthreads();
    int nz = 0;
    for (int i = threadIdx.x; i < 1024; i += 256) nz |= (p[2 * i + 1] != 0);
    if (nz) anynz = 1;   // benign race: all writers store 1
    __syncthreads();
    int isI64 = (anynz == 0);

    int base = blockIdx.x * EPB;
    for (int i = threadIdx.x; i < EPB; i += 256) {
        int s = load_idx(ei, isI64, base + i);
        int d = load_idx(ei, isI64, NE + base + i);
        sbuf[i] = s;
        dbuf[i] = d;
        atomicAdd(&cnt[d >> 8], 1);
    }
    __syncthreads();
    for (int j = threadIdx.x; j < NB; j += 256) {
        int c = cnt[j];
        int g = c ? atomicAdd(&cursor[j], c) : 0;
        basel[j] = j * CAP + g;
        cnt[j] = 0;   // reuse as local placement cursor
    }
    __syncthreads();
    for (int i = threadIdx.x; i < EPB; i += 256) {
        int s = sbuf[i];
        int d = dbuf[i];
        int bkt = d >> 8;
        int slot = basel[bkt] + atomicAdd(&cnt[bkt], 1);
        csr_tmp[slot] = ((d & 255) << 17) | s;   // dstlocal<<17 | src
    }
}

// ---------- CSR phase B: per-bucket counting sort (R22: 512 threads) ---------
__global__ __launch_bounds__(512) void k_sort(const int* __restrict__ cursor,
                                              const int* __restrict__ csr_tmp,
                                              int* __restrict__ csr,
                                              int* __restrict__ deg,
                                              int* __restrict__ offs,
                                              float* __restrict__ dis) {
    __shared__ int h[256];
    __shared__ int sc[256];
    __shared__ int cur[256];
    const int tid = threadIdx.x;
    int j = blockIdx.x;
    int s0 = j * CAP, s1 = s0 + cursor[j];
    if (tid < 256) h[tid] = 0;
    __syncthreads();
    for (int p = s0 + tid; p < s1; p += 512)
        atomicAdd(&h[csr_tmp[p] >> 17], 1);
    __syncthreads();
    int v = 0;
    if (tid < 256) { v = h[tid]; sc[tid] = v; }
    __syncthreads();
#pragma unroll
    for (int off = 1; off < 256; off <<= 1) {
        int u = 0;
        if (tid < 256 && tid >= off) u = sc[tid - off];
        __syncthreads();
        if (tid < 256) sc[tid] += u;
        __syncthreads();
    }
    if (tid < 256) {
        int excl = sc[tid] - v;
        int node = j * 256 + tid;
        if (node < NN) {
            deg[node] = v;
            offs[node] = s0 + excl;
            dis[node] = rsqrtf((float)(v + 1));  // +1 self-loop
        }
        cur[tid] = excl;
    }
    __syncthreads();
    for (int p = s0 + tid; p < s1; p += 512) {
        int pk = csr_tmp[p];
        int dl = pk >> 17;
        int pos = s0 + atomicAdd(&cur[dl], 1);
        csr[pos] = pk & 0x1FFFF;   // plain src index
    }
}

// ---------- R19: MFMA GEMM (512 thr = 8 waves, 128 nodes/block) ----------
// g[n][j] = bf16( dis[n] * (act(x)[n][:] @ W[:][j]) ), via
// mfma_f32_16x16x32_bf16. x split hi+lo bf16 (2 MFMAs) -> only W's 2^-9
// rounding adds error. Verified R9: absmax unchanged, WIN -41 us.
template <int K, int FR, bool RELU>
__global__ __launch_bounds__(512) void k_gemm_m(const float* __restrict__ x,
                                                const float* __restrict__ W,
                                                const float* __restrict__ dis,
                                                u16* __restrict__ out) {
    __shared__ u16 Ah[128 * MS];   // 10,240 B  x-hi bf16
    __shared__ u16 Al[128 * MS];   // 10,240 B  x-lo bf16
    __shared__ u16 Bw[64 * MS];    //  5,120 B  W^T bf16 [col][k]
    const int tid = threadIdx.x;
    const int w = tid >> 6;        // wave 0..7 -> M-strip rows w*16..+16
    const int l = tid & 63;
    const int row16 = l & 15;
    const int kg = l >> 4;
    const int nbase = blockIdx.x * 128;

    f32x4 acc[4];
#pragma unroll
    for (int t = 0; t < 4; ++t) acc[t] = (f32x4){0.f, 0.f, 0.f, 0.f};

    for (int kc = 0; kc < K; kc += 32) {
        // ---- stage x (fp32 -> hi/lo bf16), 8 floats/thread ----
        {
            int r = tid >> 2;          // 0..127
            int cg = tid & 3;          // 8-float group
            int n = nbase + r;
            float vs[8];
#pragma unroll
            for (int j = 0; j < 8; ++j) vs[j] = 0.f;
            if (n < NN) {
                const float* xp = x + (size_t)n * K + kc + cg * 8;
                float4 v0 = *(const float4*)xp;
                float4 v1 = *(const float4*)(xp + 4);
                vs[0] = v0.x; vs[1] = v0.y; vs[2] = v0.z; vs[3] = v0.w;
                vs[4] = v1.x; vs[5] = v1.y; vs[6] = v1.z; vs[7] = v1.w;
            }
            if (RELU) {
#pragma unroll
                for (int j = 0; j < 8; ++j) vs[j] = fmaxf(vs[j], 0.f);
            }
            u16* ah = &Ah[r * MS + cg * 8];
            u16* al = &Al[r * MS + cg * 8];
#pragma unroll
            for (int j = 0; j < 8; j += 2) {
                u16 h0 = f2bf(vs[j]);
                u16 h1 = f2bf(vs[j + 1]);
                float r0 = vs[j] - bf2f(h0);
                float r1 = vs[j + 1] - bf2f(h1);
                *(unsigned*)&ah[j] = (unsigned)h0 | ((unsigned)h1 << 16);
                *(unsigned*)&al[j] = (unsigned)f2bf(r0) | ((unsigned)f2bf(r1) << 16);
            }
        }
        // ---- stage W transposed: Bw[col][k], zero-pad cols >= FR ----
        {
            int k = tid >> 4;          // 0..31
            int c0 = (tid & 15) * 4;   // 0..60
#pragma unroll
            for (int j = 0; j < 4; ++j) {
                int c = c0 + j;
                float wv = (c < FR) ? W[(size_t)(kc + k) * FR + c] : 0.f;
                Bw[c * MS + k] = f2bf(wv);
            }
        }
        __syncthreads();
        // ---- fragments + MFMA ----
        bf16x8 ah = *(const bf16x8*)&Ah[(w * 16 + row16) * MS + kg * 8];
        bf16x8 al = *(const bf16x8*)&Al[(w * 16 + row16) * MS + kg * 8];
#pragma unroll
        for (int t = 0; t < 4; ++t) {
            bf16x8 b = *(const bf16x8*)&Bw[(t * 16 + row16) * MS + kg * 8];
            acc[t] = __builtin_amdgcn_mfma_f32_16x16x32_bf16(ah, b, acc[t], 0, 0, 0);
            acc[t] = __builtin_amdgcn_mfma_f32_16x16x32_bf16(al, b, acc[t], 0, 0, 0);
        }
        __syncthreads();
    }
    // ---- epilogue: D[row=(kg*4+r)][col=row16] -> out[n][feat] ----
#pragma unroll
    for (int r = 0; r < 4; ++r) {
        int n = nbase + w * 16 + kg * 4 + r;
        if (n < NN) {
            float dv = dis[n];
#pragma unroll
            for (int t = 0; t < 4; ++t) {
                int feat = t * 16 + row16;
                if (feat < FR)
                    out[(size_t)n * FR + feat] = f2bf(dv * acc[t][r]);
            }
        }
    }
}

// ---------- R18 gather batch: B edges, dword (feat-pair) loads ----------
// MEASURED-OPTIMAL access shape (R18/R20 A/B): quarter-wave (16 lanes x
// 4 B) = exactly one 64-B line -> 2 line-requests/row, the minimum for a
// 128-B row. u16 form (4 req) = 48 us; dword = 43.3; u64 = 45.3.
// DO NOT change the load width.
template <int F, int B, bool MASK>
__device__ __forceinline__ float2 gb2(int myidx, int i, int lim, int eh,
                                      const u16* __restrict__ g, unsigned fp) {
    unsigned off[B / 2];
#pragma unroll
    for (int k = 0; k < B / 2; ++k) {
        int s = __shfl(myidx, i + 2 * k + eh);
        off[k] = (unsigned)s * (unsigned)(F * 2) + fp * 4u;
    }
    unsigned hv[B / 2];
#pragma unroll
    for (int k = 0; k < B / 2; ++k)
        hv[k] = *(const unsigned*)((const char*)g + off[k]);
    float x0 = 0.f, x1 = 0.f, y0 = 0.f, y1 = 0.f;
#pragma unroll
    for (int k = 0; k < B / 2; ++k) {
        float vx = bf2f((u16)(hv[k] & 0xffffu));
        float vy = bf2f((u16)(hv[k] >> 16));
        if (MASK) {
            bool ok = (i + 2 * k + eh) < lim;
            vx = ok ? vx : 0.f;
            vy = ok ? vy : 0.f;
        }
        if (k & 1) { x1 += vx; y1 += vy; }
        else       { x0 += vx; y0 += vy; }
    }
    float2 r; r.x = x0 + x1; r.y = y0 + y1; return r;
}

// ---------- R18 gather: out[n][f] = dis[n]*(g[n][f] + sum_e g[src_e][f]) + b[f]
template <int F, bool SOFTMAX>
__global__ __launch_bounds__(256) void k_gather2(const int* __restrict__ offs,
                                                 const int* __restrict__ deg,
                                                 const int* __restrict__ csr,
                                                 const float* __restrict__ dis,
                                                 const u16* __restrict__ g,
                                                 const float* __restrict__ b,
                                                 float* __restrict__ out) {
    int n = blockIdx.x * 4 + (threadIdx.x >> 6);   // grid exact: n < NN
    unsigned lane = threadIdx.x & 63;
    unsigned fc2 = lane & 31;                      // feature-pair id
    int eh = (int)(lane >> 5);                     // edge-half 0/1
    bool valid = (2u * fc2 < (unsigned)F);
    unsigned fp = valid ? fc2 : (unsigned)(F / 2 - 1);

    int start = __builtin_amdgcn_readfirstlane(offs[n]);
    int len   = __builtin_amdgcn_readfirstlane(deg[n]);
    float dvn = dis[n];

    unsigned sv = *(const unsigned*)((const char*)g
                      + (size_t)(unsigned)n * (unsigned)(F * 2) + fp * 4u);
    float2 acc;
    acc.x = eh ? 0.f : bf2f((u16)(sv & 0xffffu));
    acc.y = eh ? 0.f : bf2f((u16)(sv >> 16));

    int myidx = 0;
    if ((int)lane < len) myidx = csr[start + (int)lane];
    int lim = (len < 64) ? len : 64;

    if (lim > 0) {
        float2 t;
        if (lim >= 33) {
            int i = 0;
            for (; i + 16 <= lim; i += 16) {
                t = gb2<F, 16, false>(myidx, i, lim, eh, g, fp);
                acc.x += t.x; acc.y += t.y;
            }
            if (i < lim) {
                t = gb2<F, 16, true>(myidx, i, lim, eh, g, fp);
                acc.x += t.x; acc.y += t.y;
            }
        } else if (lim >= 17) {
            t = gb2<F, 32, true>(myidx, 0, lim, eh, g, fp);
            acc.x += t.x; acc.y += t.y;
        } else if (lim == 16) {
            t = gb2<F, 16, false>(myidx, 0, lim, eh, g, fp);
            acc.x += t.x; acc.y += t.y;
        } else {
            t = gb2<F, 16, true>(myidx, 0, lim, eh, g, fp);
            acc.x += t.x; acc.y += t.y;
        }
    }
    // rare fallback: deg > 64 (halves take alternate edges)
    if (len > 64) {
        for (int i = 64 + eh; i < len; i += 2) {
            int s = csr[start + i];
            unsigned hv = *(const unsigned*)((const char*)g
                              + (unsigned)s * (unsigned)(F * 2) + fp * 4u);
            acc.x += bf2f((u16)(hv & 0xffffu));
            acc.y += bf2f((u16)(hv >> 16));
        }
    }
    acc.x += __shfl_xor(acc.x, 32);
    acc.y += __shfl_xor(acc.y, 32);

    float vx = dvn * acc.x + b[2 * fp + 0];
    float vy = dvn * acc.y + b[2 * fp + 1];

    if (!SOFTMAX) {
        if (eh == 0 && valid) {
            float2 o; o.x = vx; o.y = vy;
            *(float2*)(out + (size_t)n * F + 2 * fp) = o;
        }
    } else {
        float m = valid ? fmaxf(vx, vy) : -INFINITY;
#pragma unroll
        for (int off = 16; off; off >>= 1) m = fmaxf(m, __shfl_xor(m, off));
        float ex = valid ? (__expf(vx - m) + __expf(vy - m)) : 0.f;
        float sum = ex;
#pragma unroll
        for (int off = 16; off; off >>= 1) sum += __shfl_xor(sum, off);
        if (eh == 0 && valid) {
            float ls = logf(sum);
            float2 o; o.x = vx - m - ls; o.y = vy - m - ls;
            *(float2*)(out + (size_t)n * F + 2 * fp) = o;
        }
    }
}

extern "C" void kernel_launch(void* const* d_in, const int* in_sizes, int n_in,
                              void* d_out, int out_size, void* d_ws, size_t ws_size,
                              hipStream_t stream) {
    const float* x  = (const float*)d_in[0];
    const void*  ei = d_in[1];
    const float* W1 = (const float*)d_in[2];
    const float* b1 = (const float*)d_in[3];
    const float* W2 = (const float*)d_in[4];
    const float* b2 = (const float*)d_in[5];
    const float* W3 = (const float*)d_in[6];
    const float* b3 = (const float*)d_in[7];
    float* out = (float*)d_out;

    char* ws = (char*)d_ws;
    size_t off = 0;
    auto alloc = [&](size_t bytes) { void* p = ws + off; off += (bytes + 255) & ~255ULL; return p; };
    int*   cursor  = (int*)alloc(NB * 4);
    int*   deg     = (int*)alloc(NN * 4);
    float* dis     = (float*)alloc(NN * 4);
    int*   offs    = (int*)alloc(NN * 4);
    int*   csr_tmp = (int*)alloc((size_t)NB * CAP * 4);   // 8 MB padded
    int*   csr     = (int*)alloc((size_t)NB * CAP * 4);   // 8 MB padded
    u16*   gbuf    = (u16*)alloc((size_t)NN * 64 * 2);    // bf16 staging (12.8 MB)
    float* act     = (float*)alloc((size_t)NN * 64 * 4);  // fp32 inter-layer activations

    // CSR build: 2 kernels (padded-bucket counting sort, no global prefix)
    hipMemsetAsync(cursor, 0, NB * 4, stream);
    k_build<<<EB, 256, 0, stream>>>(ei, cursor, csr_tmp);
    k_sort<<<NB, 512, 0, stream>>>(cursor, csr_tmp, csr, deg, offs, dis);

    const int gemm_grid = (NN + 127) / 128;   // 782
    const int gather_grid = NN / 4;           // 25000 (exact)

    // layer 1: g1 = bf16(dis*(x@W1)); act = dis*(sum g1) + b1 (ReLU in next gemm)
    k_gemm_m<128, 64, false><<<gemm_grid, 512, 0, stream>>>(x, W1, dis, gbuf);
    k_gather2<64, false><<<gather_grid, 256, 0, stream>>>(offs, deg, csr, dis, gbuf, b1, act);

    // layer 2
    k_gemm_m<64, 64, true><<<gemm_grid, 512, 0, stream>>>(act, W2, dis, gbuf);
    k_gather2<64, false><<<gather_grid, 256, 0, stream>>>(offs, deg, csr, dis, gbuf, b2, act);

    // layer 3 + fused log_softmax (tight 40-wide staging rows)
    k_gemm_m<64, 40, true><<<gemm_grid, 512, 0, stream>>>(act, W3, dis, gbuf);
    k_gather2<40, true><<<gather_grid, 256, 0, stream>>>(offs, deg, csr, dis, gbuf, b3, out);
}